// Round 4
// baseline (4816.613 us; speedup 1.0000x reference)
//
#include <hip/hip_runtime.h>
#include <hip/hip_bf16.h>

// RQV residual vector-quantization — fused design, fp32 outputs, small-ws (~8.45 MB).
// Inputs (fp32): data [16,256,2048], codebooks [8,1024,256], N_i [8,1024], m_i [8,1024,256]
// Outputs (FP32 concat, return order): logits [16,256,2048], loss [1], indices [8,16,2048],
//   new_N [8,1024], new_m [8,1024,256], new_W [8,1024,256]  -> 12,853,249 floats.

#define GAMMA_F 0.99f
#define OMG_F   0.01f

// ---------- diagnostic sentinel ----------
__global__ void sentinel_kernel(float* out, float v){
  if (threadIdx.x == 0 && blockIdx.x == 0) out[0] = v;
}

// ---------- row sum-of-squares (cols = 256), one wave per row ----------
__global__ __launch_bounds__(64) void rownorm_kernel(const float* __restrict__ X,
                                                     float* __restrict__ out, int rows){
  int r = blockIdx.x;
  if (r >= rows) return;
  int l = threadIdx.x;
  const float* x = X + (size_t)r * 256;
  float s = 0.f;
  #pragma unroll
  for (int i = 0; i < 4; i++){ float v = x[l + i*64]; s += v*v; }
  #pragma unroll
  for (int o = 32; o > 0; o >>= 1) s += __shfl_down(s, o, 64);
  if (l == 0) out[r] = s;
}

// ---------- fused RVQ: 32 rows/block, resid lives in LDS across all 8 stages ----------
// LDS: rs[256][32] fp32 resid (rs[d][s_local]), Bs[16][256] swizzled codebook chunk,
//      rn_s[32] row norms, code_s[32]. Total 49,408 B -> 3 blocks/CU.
__global__ __launch_bounds__(256, 3) void rvq_kernel(
    const float* __restrict__ data, const float* __restrict__ codebooks,
    const float* __restrict__ wnorm_all,
    float* __restrict__ counts, float* __restrict__ vec, float* __restrict__ loss_acc,
    float* __restrict__ out0, float* __restrict__ out2)
{
  __shared__ float rs[256][32];
  __shared__ float Bs[16][256];
  __shared__ float rn_s[32];
  __shared__ int   code_s[32];

  const int blk = blockIdx.x;          // 0..1023
  const int b   = blk >> 6;            // batch
  const int s0  = (blk & 63) * 32;     // seq offset
  const int tid = threadIdx.x;
  const float* dptr = data + (size_t)b * 524288 + s0;   // [d][s] slab

  // transpose-in: rs[d][c] = data[b][d][s0+c]
  {
    int c = tid & 31, g = tid >> 5;    // g in 0..7
    #pragma unroll
    for (int dd = 0; dd < 32; ++dd){
      int d = g*32 + dd;
      rs[d][c] = dptr[(size_t)d * 2048 + c];
    }
  }
  __syncthreads();
  // initial per-row ||r||^2
  {
    int row = tid >> 3, k0 = (tid & 7) * 32;
    float s = 0.f;
    #pragma unroll 8
    for (int j = 0; j < 32; ++j){ float v = rs[k0 + j][row]; s += v*v; }
    s += __shfl_down(s, 4, 8); s += __shfl_down(s, 2, 8); s += __shfl_down(s, 1, 8);
    if ((tid & 7) == 0) rn_s[row] = s;
  }
  __syncthreads();

  const int tc = tid & 31, tr = tid >> 5;     // tc: code group, tr: row group
  // XOR-swizzle of quad index within a Bs row: phys = qc ^ ((qc>>3)&7)  (bijective)
  auto sw = [](int qc){ return qc ^ ((qc >> 3) & 7); };
  const int c0 = sw(2*tc)   * 4;   // phys col of logical codes tc*8..+3
  const int c1 = sw(2*tc+1) * 4;   // phys col of logical codes tc*8+4..+7
  const int lf = tid & 3, lc = tid >> 2;      // staging: lf k-quad, lc code 0..63
  const int pc0 = sw(( 0 + lc) >> 2)*4 + (lc & 3);
  const int pc1 = sw((64 + lc) >> 2)*4 + (lc & 3);
  const int pc2 = sw((128 + lc) >> 2)*4 + (lc & 3);
  const int pc3 = sw((192 + lc) >> 2)*4 + (lc & 3);

  for (int q = 0; q < 8; ++q){
    const float* Wq = codebooks + (size_t)q * 262144;
    const float* wn = wnorm_all + q * 1024;
    float bestv[4]; int besti[4];
    float rn4[4];
    #pragma unroll
    for (int i = 0; i < 4; i++){
      bestv[i] = 3.4e38f; besti[i] = 0;
      rn4[i] = rn_s[tr*4 + i];
    }

    for (int t = 0; t < 4; ++t){            // 4 code tiles of 256
      float acc[4][8];
      #pragma unroll
      for (int i = 0; i < 4; i++)
        #pragma unroll
        for (int j = 0; j < 8; j++) acc[i][j] = 0.f;

      for (int kc = 0; kc < 16; ++kc){      // K chunks of 16
        const float* gp = Wq + (size_t)(t*256 + lc) * 256 + kc*16 + lf*4;
        float4 v0 = *(const float4*)(gp);
        float4 v1 = *(const float4*)(gp +  64*256);
        float4 v2 = *(const float4*)(gp + 128*256);
        float4 v3 = *(const float4*)(gp + 192*256);
        __syncthreads();                     // prev chunk fully consumed
        {
          int k0 = lf * 4;
          Bs[k0+0][pc0]=v0.x; Bs[k0+1][pc0]=v0.y; Bs[k0+2][pc0]=v0.z; Bs[k0+3][pc0]=v0.w;
          Bs[k0+0][pc1]=v1.x; Bs[k0+1][pc1]=v1.y; Bs[k0+2][pc1]=v1.z; Bs[k0+3][pc1]=v1.w;
          Bs[k0+0][pc2]=v2.x; Bs[k0+1][pc2]=v2.y; Bs[k0+2][pc2]=v2.z; Bs[k0+3][pc2]=v2.w;
          Bs[k0+0][pc3]=v3.x; Bs[k0+1][pc3]=v3.y; Bs[k0+2][pc3]=v3.z; Bs[k0+3][pc3]=v3.w;
        }
        __syncthreads();
        #pragma unroll
        for (int kk = 0; kk < 16; ++kk){
          int k = kc*16 + kk;
          float4 av = *(const float4*)&rs[k][tr*4];
          float4 b0 = *(const float4*)&Bs[kk][c0];
          float4 b1 = *(const float4*)&Bs[kk][c1];
          float a[4]  = {av.x, av.y, av.z, av.w};
          float bb[8] = {b0.x,b0.y,b0.z,b0.w, b1.x,b1.y,b1.z,b1.w};
          #pragma unroll
          for (int i = 0; i < 4; i++)
            #pragma unroll
            for (int j = 0; j < 8; j++)
              acc[i][j] = fmaf(a[i], bb[j], acc[i][j]);
        }
      }
      // fold in rn+wn, local argmin over this tile's 8 codes per thread
      float wn8[8];
      #pragma unroll
      for (int j = 0; j < 8; j++) wn8[j] = wn[t*256 + tc*8 + j];
      #pragma unroll
      for (int i = 0; i < 4; i++){
        #pragma unroll
        for (int j = 0; j < 8; j++){
          int code = t*256 + tc*8 + j;
          float d2 = (rn4[i] + wn8[j]) - 2.0f * acc[i][j];  // np rounding order
          if (d2 < bestv[i] || (d2 == bestv[i] && code < besti[i])){ bestv[i] = d2; besti[i] = code; }
        }
      }
    }
    // butterfly argmin across the 32 tc-lanes (first-min, lowest index on ties)
    #pragma unroll
    for (int off = 16; off > 0; off >>= 1){
      #pragma unroll
      for (int i = 0; i < 4; i++){
        float ov = __shfl_xor(bestv[i], off, 32);
        int   oi = __shfl_xor(besti[i], off, 32);
        if (ov < bestv[i] || (ov == bestv[i] && oi < besti[i])){ bestv[i] = ov; besti[i] = oi; }
      }
    }
    if (tc == 0){
      #pragma unroll
      for (int i = 0; i < 4; i++){
        int row  = tr*4 + i;
        int code = besti[i];
        code_s[row] = code;
        out2[(size_t)q*32768 + (size_t)b*2048 + s0 + row] = (float)code;
        atomicAdd(&counts[q*1024 + code], 1.0f);
      }
    }
    __syncthreads();
    // update: vec[code] += stage-input resid; resid -= W[code]; next row norms
    {
      int row = tid >> 3, kq8 = (tid & 7) * 32;
      int code = code_s[row];
      const float* wrow = Wq + (size_t)code * 256 + kq8;
      float* vrow = vec + ((size_t)q*1024 + code) * 256 + kq8;
      float s = 0.f;
      #pragma unroll 4
      for (int j = 0; j < 32; ++j){
        float rold = rs[kq8 + j][row];
        atomicAdd(&vrow[j], rold);
        float rnew = rold - wrow[j];
        rs[kq8 + j][row] = rnew;
        s += rnew * rnew;
      }
      s += __shfl_down(s, 4, 8); s += __shfl_down(s, 2, 8); s += __shfl_down(s, 1, 8);
      if ((tid & 7) == 0) rn_s[row] = s;
    }
    __syncthreads();
  }

  // epilogue: logits = data - resid (fp32), loss += sum(resid^2)
  float lsum = 0.f;
  {
    int c = tid & 31, g = tid >> 5;
    float* optr = out0 + (size_t)b * 524288 + s0;
    #pragma unroll
    for (int dd = 0; dd < 32; ++dd){
      int d = g*32 + dd;
      float r = rs[d][c];
      lsum += r * r;
      optr[(size_t)d * 2048 + c] = dptr[(size_t)d * 2048 + c] - r;
    }
  }
  #pragma unroll
  for (int o = 32; o > 0; o >>= 1) lsum += __shfl_down(lsum, o, 64);
  if ((tid & 63) == 0) atomicAdd(loss_acc, lsum);
}

// ---------- EMA stats epilogue ----------
__global__ __launch_bounds__(256) void stats_kernel(
    const float* __restrict__ Ni, const float* __restrict__ mi,
    const float* __restrict__ counts, const float* __restrict__ vec,
    const float* __restrict__ loss_acc,
    float* __restrict__ outN, float* __restrict__ outM, float* __restrict__ outW,
    float* __restrict__ outLoss){
  size_t e = (size_t)blockIdx.x * 256 + threadIdx.x;
  if (e >= 2097152ull) return;
  int qn = (int)(e >> 8);
  float Nn = Ni[qn] * GAMMA_F + counts[qn] * OMG_F;
  float mn = mi[e]  * GAMMA_F + vec[e]    * OMG_F;
  outM[e] = mn;
  outW[e] = mn / fmaxf(Nn, 1e-8f);
  if ((e & 255) == 0) outN[qn] = Nn;
  if (e == 0) outLoss[0] = loss_acc[0] * (1.0f / 8388608.0f);
}

extern "C" void kernel_launch(void* const* d_in, const int* in_sizes, int n_in,
                              void* d_out, int out_size, void* d_ws, size_t ws_size,
                              hipStream_t stream){
  float* out = (float*)d_out;   // reference outputs are float32

  // ---- size-keyed input binding (robust to harness input-ordering) ----
  const float* data = nullptr; const float* codebooks = nullptr;
  const float* Ni = nullptr;   const float* mi = nullptr;
  for (int i = 0; i < n_in; ++i){
    if      (in_sizes[i] == 8388608) data = (const float*)d_in[i];
    else if (in_sizes[i] == 8192)    Ni   = (const float*)d_in[i];
    else if (in_sizes[i] == 2097152){
      if (!codebooks) codebooks = (const float*)d_in[i];
      else            mi        = (const float*)d_in[i];
    }
  }
  if (!data || !codebooks || !Ni || !mi){
    sentinel_kernel<<<1, 64, 0, stream>>>(out, 6666.0f);   // binding failure signature
    return;
  }

  // ws layout (fp32) — total 8,454,148 bytes
  const size_t ws_need = sizeof(float) * (8192ull + 8192ull + 2097152ull + 1ull);
  if (ws_size < ws_need){
    sentinel_kernel<<<1, 64, 0, stream>>>(out, 7777.0f);   // ws-too-small signature
    return;
  }
  float* wnormb   = (float*)d_ws;            // 8192
  float* counts   = wnormb + 8192;           // 8192     (zeroed)
  float* vec      = counts + 8192;           // 2097152  (zeroed)
  float* loss_acc = vec + 2097152;           // 1        (zeroed)

  // out offsets (fp32 elements, reference return order)
  float* out0 = out;                  // logits  8388608
  float* out1 = out0 + 8388608;       // loss    1
  float* out2 = out1 + 1;             // indices 262144
  float* out3 = out2 + 262144;        // new_N   8192
  float* out4 = out3 + 8192;          // new_m   2097152
  float* out5 = out4 + 2097152;       // new_W   2097152

  hipMemsetAsync(counts, 0, sizeof(float) * (8192 + 2097152 + 1), stream);

  rownorm_kernel<<<dim3(8192), 64, 0, stream>>>(codebooks, wnormb, 8192);

  rvq_kernel<<<dim3(1024), 256, 0, stream>>>(data, codebooks, wnormb,
                                             counts, vec, loss_acc, out0, out2);

  stats_kernel<<<dim3(8192), 256, 0, stream>>>(Ni, mi, counts, vec, loss_acc,
                                               out3, out4, out5, out1);
}